// Round 5
// baseline (793.796 us; speedup 1.0000x reference)
//
#include <hip/hip_runtime.h>
#include <math.h>

// DisenTripletGCN — MFMA bf16 GEMMs, CSR-slot pooling (no atomics) when ws
// allows, reg-cached routing.
// ws layout (bytes):
//   Xh    @ 0           : 80000*512 bf16 = 81,920,000
//   Uh2   @ 81,920,000  : 20000*512 bf16 = 20,480,000
//   OVL   @ 102,400,000 : 20,480,000  (predh | Uh1 | PL — disjoint lifetimes:
//                          predh: cvt->gemm0; Uh1: rout1->rout2 (both phases);
//                          PL: pool->gemm2)
//   Wt1   @ 122,880,000 : 512x384 bf16
//   Wt2   @ 123,273,216 : 768x512 bf16
//   Wt3   @ 124,059,648 : 512x256 bf16
//   Wt4   @ 124,321,792 : 256x512 bf16
//   I     @ 124,583,936 : 360,002 ints (CSR + slots)  -> end 126,023,944
//   val_s @ 126,024,000 : 80000*256 bf16 = 40,960,000   (big-ws path only)
//   val_o @ 166,984,000 : 80000*256 bf16 = 40,960,000   -> end 207,944,000
// base footprint 126.0 MB (< proven 144.5); SO path needs ws >= 207,944,000.

#define O_N 20000
#define T_N 80000
#define BIG_REQ 207944000ull

typedef unsigned short bf_t;
typedef bf_t bfx4 __attribute__((ext_vector_type(4)));
typedef bf_t bfx8 __attribute__((ext_vector_type(8)));
typedef __attribute__((ext_vector_type(4))) float f32x4;
typedef __attribute__((ext_vector_type(8))) short s16x8;

#define AS1 __attribute__((address_space(1)))
#define AS3 __attribute__((address_space(3)))

__device__ __forceinline__ float leaky(float y) { return y > 0.0f ? y : 0.01f * y; }
__device__ __forceinline__ float bf2f(bf_t u) {
  union { unsigned int i; float f; } v; v.i = ((unsigned int)u) << 16; return v.f;
}
__device__ __forceinline__ bf_t f2bf(float f) {
  union { float f; unsigned int i; } v; v.f = f;
  unsigned int b = v.i;
  return (bf_t)((b + 0x7FFFu + ((b >> 16) & 1u)) >> 16);  // RNE
}
__device__ __forceinline__ void gload16(const bf_t* g, bf_t* l) {
  __builtin_amdgcn_global_load_lds((const AS1 void*)g, (AS3 void*)l, 16, 0, 0);
}

// ---------------- CSR build ----------------
__global__ void count_kernel(const int* __restrict__ edges, int* cnt_s, int* cnt_o) {
  int m = blockIdx.x * blockDim.x + threadIdx.x;
  if (m < T_N) {
    atomicAdd(&cnt_s[edges[2 * m]], 1);
    atomicAdd(&cnt_o[edges[2 * m + 1]], 1);
  }
}

__global__ void scan_kernel(const int* __restrict__ cnt_s, const int* __restrict__ cnt_o,
                            int* offs_s, int* cur_s, int* offs_o, int* cur_o) {
  const int n = O_N;
  const int* cnt = (blockIdx.x == 0) ? cnt_s : cnt_o;
  int* offs = (blockIdx.x == 0) ? offs_s : offs_o;
  int* cur  = (blockIdx.x == 0) ? cur_s  : cur_o;
  __shared__ int lds[1024];
  __shared__ int sbase;
  if (threadIdx.x == 0) sbase = 0;
  __syncthreads();
  for (int start = 0; start < n; start += 1024) {
    int i = start + (int)threadIdx.x;
    int v = (i < n) ? cnt[i] : 0;
    lds[threadIdx.x] = v;
    __syncthreads();
    for (int off = 1; off < 1024; off <<= 1) {
      int t = (threadIdx.x >= (unsigned)off) ? lds[threadIdx.x - off] : 0;
      __syncthreads();
      lds[threadIdx.x] += t;
      __syncthreads();
    }
    int base = sbase;
    int excl = base + lds[threadIdx.x] - v;
    if (i < n) { offs[i] = excl; cur[i] = excl; }
    __syncthreads();
    if (threadIdx.x == 1023) sbase = base + lds[1023];
    __syncthreads();
  }
  if (threadIdx.x == 0) offs[n] = sbase;
}

__global__ void fill_kernel(const int* __restrict__ edges, int* cur_s, int* cur_o,
                            int* srcs, int* slot_s, int* slot_o) {
  int m = blockIdx.x * blockDim.x + threadIdx.x;
  if (m < T_N) {
    int s = edges[2 * m], o = edges[2 * m + 1];
    int ps = atomicAdd(&cur_s[s], 1);
    slot_s[m] = ps;
    int po = atomicAdd(&cur_o[o], 1);
    slot_o[m] = po;
    srcs[po] = s;
  }
}

// ---------------- pred f32 -> bf16 ----------------
__global__ void cvt_pred(const float* __restrict__ src, bf_t* __restrict__ dst, int n8) {
  int i = blockIdx.x * blockDim.x + threadIdx.x;
  if (i >= n8) return;
  float4 a = ((const float4*)src)[2 * i];
  float4 b = ((const float4*)src)[2 * i + 1];
  bfx8 w;
  w[0] = f2bf(a.x); w[1] = f2bf(a.y); w[2] = f2bf(a.z); w[3] = f2bf(a.w);
  w[4] = f2bf(b.x); w[5] = f2bf(b.y); w[6] = f2bf(b.z); w[7] = f2bf(b.w);
  *(bfx8*)(dst + (size_t)i * 8) = w;
}

// ---------------- weight transpose + cvt: W[K][N] f32 -> Wt[N][K] bf16 ----------------
__global__ void transpose_cvt(const float* __restrict__ W, bf_t* __restrict__ Wt, int K, int N) {
  __shared__ float t[32][33];
  int kb = blockIdx.y << 5, nb = blockIdx.x << 5;
  int tx = threadIdx.x, ty = threadIdx.y;  // 32 x 8
#pragma unroll
  for (int r = 0; r < 32; r += 8) t[ty + r][tx] = W[(size_t)(kb + ty + r) * N + nb + tx];
  __syncthreads();
#pragma unroll
  for (int r = 0; r < 32; r += 8) Wt[(size_t)(nb + ty + r) * K + kb + tx] = f2bf(t[tx][ty + r]);
}

// stage 16 f32 -> 2 swizzled bfx8 LDS chunks
__device__ __forceinline__ void stage16(const float* base, bf_t* stA, int slot0) {
  float4 q0 = ((const float4*)base)[0];
  float4 q1 = ((const float4*)base)[1];
  float4 q2 = ((const float4*)base)[2];
  float4 q3 = ((const float4*)base)[3];
  bfx8 w0, w1;
  w0[0] = f2bf(q0.x); w0[1] = f2bf(q0.y); w0[2] = f2bf(q0.z); w0[3] = f2bf(q0.w);
  w0[4] = f2bf(q1.x); w0[5] = f2bf(q1.y); w0[6] = f2bf(q1.z); w0[7] = f2bf(q1.w);
  w1[0] = f2bf(q2.x); w1[1] = f2bf(q2.y); w1[2] = f2bf(q2.z); w1[3] = f2bf(q2.w);
  w1[4] = f2bf(q3.x); w1[5] = f2bf(q3.y); w1[6] = f2bf(q3.z); w1[7] = f2bf(q3.w);
  *(bfx8*)(stA + slot0 * 8) = w0;
  *(bfx8*)(stA + (slot0 ^ 1) * 8) = w1;
}

// ---------------- MFMA GEMM: C[M,N] = A[M,K](bf16) x Wt[N,K](bf16), 128x128 tile ----------------
// MODE 0 (pca1): A = [obj[s] f32 | predh bf16 DMA | obj[o] f32], K=384; epi: +b, leaky, capsule-l2norm -> Xh
// MODE 1 (clf1, atomic pooling): A = m<O_N?Uh2:Xh DMA; epi: bn+leaky; atomicAdd PL / pred_out
// MODE 2 (pca2): A = PL f32 reg-staged; epi like MODE 0 -> Xh
// MODE 3 (clf2): A = Uh2 DMA; epi: bn+leaky -> obj_out f32
// MODE 4 (clf1, slot pooling):  A like MODE 1; epi: val_s[slot_s[m]] / pred_out / val_o[slot_o[m]]
template <int MODE>
__global__ __launch_bounds__(256) void gemm_mfma(
    const bf_t* __restrict__ Ah, const bf_t* __restrict__ Axh,
    const float* __restrict__ Af, const float* __restrict__ obj,
    const int* __restrict__ edges,
    const bf_t* __restrict__ Wt, const float* __restrict__ bias,
    const float* __restrict__ bng, const float* __restrict__ bnb,
    bf_t* __restrict__ outh, float* __restrict__ outf, float* __restrict__ pool,
    bf_t* __restrict__ vs, bf_t* __restrict__ vo,
    const int* __restrict__ slot_s, const int* __restrict__ slot_o,
    int M, int N, int K) {
  __shared__ __align__(16) bf_t As[128 * 32];
  __shared__ __align__(16) bf_t Bs[128 * 32];

  const int tid = threadIdx.x;
  const int w = tid >> 6, l = tid & 63;
  const int wr = w >> 1, wc = w & 1;
  const int row0 = blockIdx.y * 128, col0 = blockIdx.x * 128;

  // --- staging pointers (DMA: wave-uniform LDS dest + per-lane global src) ---
  const int srow = l >> 2;
  const int skb = ((l & 3) ^ (srow & 3) ^ ((srow >> 2) & 3)) * 8;  // swizzled src k-chunk
  const bf_t* pB[2];
  bf_t* ldsB[2];
  bf_t* ldsA[2];
  const bf_t* pA[2];
#pragma unroll
  for (int j = 0; j < 2; ++j) {
    int n = col0 + j * 64 + w * 16 + srow;
    pB[j] = Wt + (size_t)n * K + skb;
    ldsB[j] = Bs + (j * 64 + w * 16) * 32;
    ldsA[j] = As + (j * 64 + w * 16) * 32;
  }
  if constexpr (MODE == 1 || MODE == 3 || MODE == 4) {
#pragma unroll
    for (int j = 0; j < 2; ++j) {
      int m = row0 + j * 64 + w * 16 + srow;
      if (MODE == 3) m = min(m, M - 1);
      const bf_t* base = (MODE == 3) ? Ah : ((m < O_N) ? Ah : Axh);
      pA[j] = base + (size_t)m * 512 + skb;
    }
  }
  // reg-staging thread constants
  const int r_ = tid >> 1, h_ = tid & 1;
  const int slot0_ = (2 * h_) ^ (r_ & 3) ^ ((r_ >> 2) & 3);
  bf_t* stA = As + r_ * 32;
  int sIdx = 0, oIdx = 0, mrow = 0;
  if constexpr (MODE == 0) {
    mrow = row0 + r_;
    sIdx = edges[2 * mrow];
    oIdx = edges[2 * mrow + 1];
#pragma unroll
    for (int j = 0; j < 2; ++j)
      pA[j] = Ah + (size_t)(row0 + j * 64 + w * 16 + srow) * 128 + skb;  // predh
  }
  if constexpr (MODE == 2) mrow = min(row0 + r_, M - 1);

  // --- fragment read offsets ---
  const int pkb = ((l >> 4) ^ (l & 3) ^ ((l >> 2) & 3)) * 8;
  int aoff[4], boff[4];
#pragma unroll
  for (int i = 0; i < 4; ++i) {
    aoff[i] = (wr * 64 + i * 16 + (l & 15)) * 32 + pkb;
    boff[i] = (wc * 64 + i * 16 + (l & 15)) * 32 + pkb;
  }

  f32x4 acc[4][4];
  const f32x4 z4 = {0.f, 0.f, 0.f, 0.f};
#pragma unroll
  for (int i = 0; i < 4; ++i)
#pragma unroll
    for (int j = 0; j < 4; ++j) acc[i][j] = z4;

  // --- K loop ---
  for (int k0 = 0; k0 < K; k0 += 32) {
    if (k0) __syncthreads();
#pragma unroll
    for (int j = 0; j < 2; ++j) { gload16(pB[j], ldsB[j]); pB[j] += 32; }
    if constexpr (MODE == 1 || MODE == 3 || MODE == 4) {
#pragma unroll
      for (int j = 0; j < 2; ++j) { gload16(pA[j], ldsA[j]); pA[j] += 32; }
    } else if constexpr (MODE == 0) {
      if (k0 >= 128 && k0 < 256) {
        gload16(pA[0] + (k0 - 128), ldsA[0]);
        gload16(pA[1] + (k0 - 128), ldsA[1]);
      } else {
        const float* base = (k0 < 128)
            ? obj + (size_t)sIdx * 128 + k0 + h_ * 16
            : obj + (size_t)oIdx * 128 + (k0 - 256) + h_ * 16;
        stage16(base, stA, slot0_);
      }
    } else {  // MODE 2
      stage16(Af + (size_t)mrow * K + k0 + h_ * 16, stA, slot0_);
    }
    __syncthreads();
    s16x8 a[4], b[4];
#pragma unroll
    for (int i = 0; i < 4; ++i) a[i] = *(const s16x8*)(As + aoff[i]);
#pragma unroll
    for (int i = 0; i < 4; ++i) b[i] = *(const s16x8*)(Bs + boff[i]);
#pragma unroll
    for (int mi = 0; mi < 4; ++mi)
#pragma unroll
      for (int ni = 0; ni < 4; ++ni)
        acc[mi][ni] = __builtin_amdgcn_mfma_f32_16x16x32_bf16(a[mi], b[ni], acc[mi][ni], 0, 0, 0);
  }

  // --- epilogue ---
  const int lg = l >> 4, li = l & 15;
  const float invs = 1.0f / sqrtf(1.0f + 1e-5f);
  int ncol[4];
  float bsv[4], bgv[4], bbv[4];
#pragma unroll
  for (int ni = 0; ni < 4; ++ni) {
    int n = col0 + wc * 64 + ni * 16 + li;
    ncol[ni] = n;
    bsv[ni] = bias[n];
    if constexpr (MODE == 1 || MODE == 3 || MODE == 4) { bgv[ni] = bng[n] * invs; bbv[ni] = bnb[n]; }
  }
  if constexpr (MODE == 0 || MODE == 2) {
#pragma unroll
    for (int mi = 0; mi < 4; ++mi) {
#pragma unroll
      for (int rg = 0; rg < 4; ++rg) {
        int m = row0 + wr * 64 + mi * 16 + lg * 4 + rg;
        float y[4], ssq = 0.f;
#pragma unroll
        for (int ni = 0; ni < 4; ++ni) {
          float v = leaky(acc[mi][ni][rg] + bsv[ni]);
          y[ni] = v; ssq += v * v;
        }
        ssq += __shfl_xor(ssq, 1); ssq += __shfl_xor(ssq, 2);
        ssq += __shfl_xor(ssq, 4); ssq += __shfl_xor(ssq, 8);
        if (MODE == 2 && m >= M) continue;
        float inv = 1.0f / fmaxf(sqrtf(ssq), 1e-12f);
#pragma unroll
        for (int ni = 0; ni < 4; ++ni)
          outh[(size_t)m * 512 + ncol[ni]] = f2bf(y[ni] * inv);
      }
    }
  } else if constexpr (MODE == 1) {
#pragma unroll
    for (int mi = 0; mi < 4; ++mi) {
#pragma unroll
      for (int rg = 0; rg < 4; ++rg) {
        int m = row0 + wr * 64 + mi * 16 + lg * 4 + rg;
        int sI = edges[2 * m], oI = edges[2 * m + 1];
#pragma unroll
        for (int ni = 0; ni < 4; ++ni) {
          int n = ncol[ni];
          float v = leaky((acc[mi][ni][rg] + bsv[ni]) * bgv[ni] + bbv[ni]);
          if (n < 256)      atomicAdd(&pool[(size_t)sI * 256 + n], v);
          else if (n < 512) outf[(size_t)m * 256 + (n - 256)] = v;
          else              atomicAdd(&pool[(size_t)oI * 256 + (n - 512)], v);
        }
      }
    }
  } else if constexpr (MODE == 4) {
#pragma unroll
    for (int mi = 0; mi < 4; ++mi) {
#pragma unroll
      for (int rg = 0; rg < 4; ++rg) {
        int m = row0 + wr * 64 + mi * 16 + lg * 4 + rg;
        int ss = slot_s[m], so = slot_o[m];
#pragma unroll
        for (int ni = 0; ni < 4; ++ni) {
          int n = ncol[ni];
          float v = leaky((acc[mi][ni][rg] + bsv[ni]) * bgv[ni] + bbv[ni]);
          if (n < 256)      vs[(size_t)ss * 256 + n] = f2bf(v);
          else if (n < 512) outf[(size_t)m * 256 + (n - 256)] = v;
          else              vo[(size_t)so * 256 + (n - 512)] = f2bf(v);
        }
      }
    }
  } else {
#pragma unroll
    for (int mi = 0; mi < 4; ++mi) {
#pragma unroll
      for (int rg = 0; rg < 4; ++rg) {
        int m = row0 + wr * 64 + mi * 16 + lg * 4 + rg;
        if (m >= M) continue;
#pragma unroll
        for (int ni = 0; ni < 4; ++ni) {
          float v = leaky((acc[mi][ni][rg] + bsv[ni]) * bgv[ni] + bbv[ni]);
          outf[(size_t)m * 256 + ncol[ni]] = v;
        }
      }
    }
  }
}

// ---------------- CSR-ordered pooling (no atomics) + divide ----------------
__global__ __launch_bounds__(256) void pool_so(
    const bf_t* __restrict__ vs, const bf_t* __restrict__ vo,
    const int* __restrict__ offs_s, const int* __restrict__ offs_o,
    float* __restrict__ PL, int nnodes) {
  int v = blockIdx.x * 4 + ((int)threadIdx.x >> 6);
  int lane = threadIdx.x & 63;
  if (v >= nnodes) return;
  float sx = 0, sy = 0, sz = 0, sw = 0;
  int a0 = offs_s[v], a1 = offs_s[v + 1];
  for (int e = a0; e < a1; ++e) {
    bfx4 t = *(const bfx4*)(vs + (size_t)e * 256 + lane * 4);
    sx += bf2f(t[0]); sy += bf2f(t[1]); sz += bf2f(t[2]); sw += bf2f(t[3]);
  }
  int b0 = offs_o[v], b1 = offs_o[v + 1];
  for (int e = b0; e < b1; ++e) {
    bfx4 t = *(const bfx4*)(vo + (size_t)e * 256 + lane * 4);
    sx += bf2f(t[0]); sy += bf2f(t[1]); sz += bf2f(t[2]); sw += bf2f(t[3]);
  }
  float inv = 1.0f / fmaxf((float)((a1 - a0) + (b1 - b0)), 1.0f);
  float4 r = {sx * inv, sy * inv, sz * inv, sw * inv};
  *(float4*)(PL + (size_t)v * 256 + lane * 4) = r;
}

// ---------------- per-edge softmax step (shared by both rout paths) ----------------
#define EDGE_STEP(ZR)                                                                   \
  {                                                                                     \
    float d = 0.0f;                                                                     \
    _Pragma("unroll") for (int q = 0; q < 8; ++q) d += (ZR)[q] * ur[q];                 \
    d += __shfl_xor(d, 1); d += __shfl_xor(d, 2); d += __shfl_xor(d, 4);                \
    float mx = d;                                                                       \
    mx = fmaxf(mx, __shfl_xor(mx, 8));                                                  \
    mx = fmaxf(mx, __shfl_xor(mx, 16));                                                 \
    mx = fmaxf(mx, __shfl_xor(mx, 32));                                                 \
    float ex = expf(d - mx);                                                            \
    float sm = ex;                                                                      \
    sm += __shfl_xor(sm, 8); sm += __shfl_xor(sm, 16); sm += __shfl_xor(sm, 32);        \
    float pk = ex / sm;                                                                 \
    _Pragma("unroll") for (int q = 0; q < 8; ++q) ag[q] += pk * (ZR)[q];                \
  }

// ---------------- fused routing layer: wave per node, 3 iters in-register ----------------
__global__ __launch_bounds__(256) void rout_layer(
    const bf_t* __restrict__ Z, bf_t* __restrict__ U,
    const int* __restrict__ offs, const int* __restrict__ srcs, int nnodes) {
  int v = blockIdx.x * 4 + ((int)threadIdx.x >> 6);
  int lane = threadIdx.x & 63;
  if (v >= nnodes) return;
  bfx8 xv = *(const bfx8*)(Z + (size_t)v * 512 + lane * 8);
  float xr[8], ur[8];
#pragma unroll
  for (int q = 0; q < 8; ++q) { xr[q] = bf2f(xv[q]); ur[q] = xr[q]; }
  int e0 = offs[v], e1 = offs[v + 1], deg = e1 - e0;
  if (deg <= 8) {
    bfx8 zc[8];
#pragma unroll
    for (int e = 0; e < 8; ++e)
      if (e < deg) zc[e] = *(const bfx8*)(Z + (size_t)srcs[e0 + e] * 512 + lane * 8);
    for (int it = 0; it < 3; ++it) {
      float ag[8] = {0, 0, 0, 0, 0, 0, 0, 0};
#pragma unroll
      for (int e = 0; e < 8; ++e)
        if (e < deg) {
          float zr[8];
#pragma unroll
          for (int q = 0; q < 8; ++q) zr[q] = bf2f(zc[e][q]);
          EDGE_STEP(zr);
        }
      float ss = 0.0f, wv[8];
#pragma unroll
      for (int q = 0; q < 8; ++q) { wv[q] = ag[q] + xr[q]; ss += wv[q] * wv[q]; }
      ss += __shfl_xor(ss, 1); ss += __shfl_xor(ss, 2); ss += __shfl_xor(ss, 4);
      float inv = 1.0f / fmaxf(sqrtf(ss), 1e-12f);
#pragma unroll
      for (int q = 0; q < 8; ++q) ur[q] = wv[q] * inv;
    }
  } else {
    for (int it = 0; it < 3; ++it) {
      float ag[8] = {0, 0, 0, 0, 0, 0, 0, 0};
      for (int e = e0; e < e1; ++e) {
        bfx8 zv = *(const bfx8*)(Z + (size_t)srcs[e] * 512 + lane * 8);
        float zr[8];
#pragma unroll
        for (int q = 0; q < 8; ++q) zr[q] = bf2f(zv[q]);
        EDGE_STEP(zr);
      }
      float ss = 0.0f, wv[8];
#pragma unroll
      for (int q = 0; q < 8; ++q) { wv[q] = ag[q] + xr[q]; ss += wv[q] * wv[q]; }
      ss += __shfl_xor(ss, 1); ss += __shfl_xor(ss, 2); ss += __shfl_xor(ss, 4);
      float inv = 1.0f / fmaxf(sqrtf(ss), 1e-12f);
#pragma unroll
      for (int q = 0; q < 8; ++q) ur[q] = wv[q] * inv;
    }
  }
  bfx8 ov;
#pragma unroll
  for (int q = 0; q < 8; ++q) ov[q] = f2bf(ur[q]);
  *(bfx8*)(U + (size_t)v * 512 + lane * 8) = ov;
}

// ---------------- pooled /= max(degree,1) (atomic fallback path) ----------------
__global__ void divide_kernel(float* __restrict__ PL,
                              const int* __restrict__ offs_s, const int* __restrict__ offs_o) {
  int v = blockIdx.x;
  int c = threadIdx.x;
  float cnt = (float)((offs_s[v + 1] - offs_s[v]) + (offs_o[v + 1] - offs_o[v]));
  PL[(size_t)v * 256 + c] *= 1.0f / fmaxf(cnt, 1.0f);
}

extern "C" void kernel_launch(void* const* d_in, const int* in_sizes, int n_in,
                              void* d_out, int out_size, void* d_ws, size_t ws_size,
                              hipStream_t stream) {
  const float* obj    = (const float*)d_in[0];
  const float* pred   = (const float*)d_in[1];
  const int*   edges  = (const int*)d_in[2];
  const float* pca_w1 = (const float*)d_in[3];
  const float* pca_b1 = (const float*)d_in[4];
  const float* clf_w1 = (const float*)d_in[5];
  const float* clf_b1 = (const float*)d_in[6];
  const float* bn_g1  = (const float*)d_in[7];
  const float* bn_b1  = (const float*)d_in[8];
  const float* pca_w2 = (const float*)d_in[9];
  const float* pca_b2 = (const float*)d_in[10];
  const float* clf_w2 = (const float*)d_in[11];
  const float* clf_b2 = (const float*)d_in[12];
  const float* bn_g2  = (const float*)d_in[13];
  const float* bn_b2  = (const float*)d_in[14];
  float* outp = (float*)d_out;

  char* ws = (char*)d_ws;
  bf_t* Xh    = (bf_t*)ws;
  bf_t* Uh2   = (bf_t*)(ws + 81920000);
  bf_t* predh = (bf_t*)(ws + 102400000);  // overlay: predh | Uh1 | PL
  bf_t* Uh1   = (bf_t*)(ws + 102400000);
  float* PL   = (float*)(ws + 102400000);
  bf_t* Wt1   = (bf_t*)(ws + 122880000);
  bf_t* Wt2   = (bf_t*)(ws + 123273216);
  bf_t* Wt3   = (bf_t*)(ws + 124059648);
  bf_t* Wt4   = (bf_t*)(ws + 124321792);
  int* I      = (int*)(ws + 124583936);
  int* cnt_s  = I;            int* cnt_o  = I + 20000;
  int* offs_s = I + 40000;    int* offs_o = I + 60001;
  int* cur_s  = I + 80002;    int* cur_o  = I + 100002;
  int* srcs   = I + 120002;
  int* slot_s = I + 200002;   int* slot_o = I + 280002;
  bf_t* val_s = (bf_t*)(ws + 126024000);
  bf_t* val_o = (bf_t*)(ws + 166984000);
  const bool big = (ws_size >= BIG_REQ);

  hipMemsetAsync(cnt_s, 0, 160000, stream);
  count_kernel<<<313, 256, 0, stream>>>(edges, cnt_s, cnt_o);
  scan_kernel<<<2, 1024, 0, stream>>>(cnt_s, cnt_o, offs_s, cur_s, offs_o, cur_o);
  fill_kernel<<<313, 256, 0, stream>>>(edges, cur_s, cur_o, srcs, slot_s, slot_o);

  cvt_pred<<<5000, 256, 0, stream>>>(pred, predh, 1280000);
  transpose_cvt<<<dim3(16, 12), dim3(32, 8), 0, stream>>>(pca_w1, Wt1, 384, 512);
  transpose_cvt<<<dim3(24, 16), dim3(32, 8), 0, stream>>>(clf_w1, Wt2, 512, 768);
  transpose_cvt<<<dim3(16, 8),  dim3(32, 8), 0, stream>>>(pca_w2, Wt3, 256, 512);
  transpose_cvt<<<dim3(8, 16),  dim3(32, 8), 0, stream>>>(clf_w2, Wt4, 512, 256);

  // ---- phase 1 ----
  gemm_mfma<0><<<dim3(4, 625), 256, 0, stream>>>(predh, nullptr, nullptr, obj, edges,
                                                 Wt1, pca_b1, nullptr, nullptr,
                                                 Xh, nullptr, nullptr, nullptr, nullptr,
                                                 nullptr, nullptr, T_N, 512, 384);
  rout_layer<<<5000, 256, 0, stream>>>(Xh, Uh1, offs_o, srcs, O_N);
  rout_layer<<<5000, 256, 0, stream>>>(Uh1, Uh2, offs_o, srcs, O_N);
  if (big) {
    gemm_mfma<4><<<dim3(6, 625), 256, 0, stream>>>(Uh2, Xh, nullptr, nullptr, edges,
                                                   Wt2, clf_b1, bn_g1, bn_b1,
                                                   nullptr, outp + 5120000, nullptr, val_s, val_o,
                                                   slot_s, slot_o, T_N, 768, 512);
    pool_so<<<5000, 256, 0, stream>>>(val_s, val_o, offs_s, offs_o, PL, O_N);
  } else {
    hipMemsetAsync(PL, 0, 20480000, stream);
    gemm_mfma<1><<<dim3(6, 625), 256, 0, stream>>>(Uh2, Xh, nullptr, nullptr, edges,
                                                   Wt2, clf_b1, bn_g1, bn_b1,
                                                   nullptr, outp + 5120000, PL, nullptr, nullptr,
                                                   nullptr, nullptr, T_N, 768, 512);
    divide_kernel<<<O_N, 256, 0, stream>>>(PL, offs_s, offs_o);
  }

  // ---- phase 2 (Xh reused as X2) ----
  gemm_mfma<2><<<dim3(4, 157), 256, 0, stream>>>(nullptr, nullptr, PL, nullptr, nullptr,
                                                 Wt3, pca_b2, nullptr, nullptr,
                                                 Xh, nullptr, nullptr, nullptr, nullptr,
                                                 nullptr, nullptr, O_N, 512, 256);
  rout_layer<<<5000, 256, 0, stream>>>(Xh, Uh1, offs_o, srcs, O_N);
  rout_layer<<<5000, 256, 0, stream>>>(Uh1, Uh2, offs_o, srcs, O_N);
  gemm_mfma<3><<<dim3(2, 157), 256, 0, stream>>>(Uh2, nullptr, nullptr, nullptr, nullptr,
                                                 Wt4, clf_b2, bn_g2, bn_b2,
                                                 nullptr, outp, nullptr, nullptr, nullptr,
                                                 nullptr, nullptr, O_N, 256, 512);
}

// Round 6
// 767.157 us; speedup vs baseline: 1.0347x; 1.0347x over previous
//
#include <hip/hip_runtime.h>
#include <math.h>

// DisenTripletGCN — MFMA bf16 GEMMs + XCD-grouped block swizzle (A-panel L2 reuse),
// CSR-slot pooling (no atomics) when ws allows, reg-cached routing.
// ws layout: see round-5 (unchanged). Base 126.0 MB; SO path needs >= 207,944,000 B.

#define O_N 20000
#define T_N 80000
#define BIG_REQ 207944000ull

typedef unsigned short bf_t;
typedef bf_t bfx4 __attribute__((ext_vector_type(4)));
typedef bf_t bfx8 __attribute__((ext_vector_type(8)));
typedef __attribute__((ext_vector_type(4))) float f32x4;
typedef __attribute__((ext_vector_type(8))) short s16x8;

#define AS1 __attribute__((address_space(1)))
#define AS3 __attribute__((address_space(3)))

__device__ __forceinline__ float leaky(float y) { return y > 0.0f ? y : 0.01f * y; }
__device__ __forceinline__ float bf2f(bf_t u) {
  union { unsigned int i; float f; } v; v.i = ((unsigned int)u) << 16; return v.f;
}
__device__ __forceinline__ bf_t f2bf(float f) {
  union { float f; unsigned int i; } v; v.f = f;
  unsigned int b = v.i;
  return (bf_t)((b + 0x7FFFu + ((b >> 16) & 1u)) >> 16);  // RNE
}
__device__ __forceinline__ void gload16(const bf_t* g, bf_t* l) {
  __builtin_amdgcn_global_load_lds((const AS1 void*)g, (AS3 void*)l, 16, 0, 0);
}

// ---------------- CSR build ----------------
__global__ void count_kernel(const int* __restrict__ edges, int* cnt_s, int* cnt_o) {
  int m = blockIdx.x * blockDim.x + threadIdx.x;
  if (m < T_N) {
    atomicAdd(&cnt_s[edges[2 * m]], 1);
    atomicAdd(&cnt_o[edges[2 * m + 1]], 1);
  }
}

__global__ void scan_kernel(const int* __restrict__ cnt_s, const int* __restrict__ cnt_o,
                            int* offs_s, int* cur_s, int* offs_o, int* cur_o) {
  const int n = O_N;
  const int* cnt = (blockIdx.x == 0) ? cnt_s : cnt_o;
  int* offs = (blockIdx.x == 0) ? offs_s : offs_o;
  int* cur  = (blockIdx.x == 0) ? cur_s  : cur_o;
  __shared__ int lds[1024];
  __shared__ int sbase;
  if (threadIdx.x == 0) sbase = 0;
  __syncthreads();
  for (int start = 0; start < n; start += 1024) {
    int i = start + (int)threadIdx.x;
    int v = (i < n) ? cnt[i] : 0;
    lds[threadIdx.x] = v;
    __syncthreads();
    for (int off = 1; off < 1024; off <<= 1) {
      int t = (threadIdx.x >= (unsigned)off) ? lds[threadIdx.x - off] : 0;
      __syncthreads();
      lds[threadIdx.x] += t;
      __syncthreads();
    }
    int base = sbase;
    int excl = base + lds[threadIdx.x] - v;
    if (i < n) { offs[i] = excl; cur[i] = excl; }
    __syncthreads();
    if (threadIdx.x == 1023) sbase = base + lds[1023];
    __syncthreads();
  }
  if (threadIdx.x == 0) offs[n] = sbase;
}

__global__ void fill_kernel(const int* __restrict__ edges, int* cur_s, int* cur_o,
                            int* srcs, int* slot_s, int* slot_o) {
  int m = blockIdx.x * blockDim.x + threadIdx.x;
  if (m < T_N) {
    int s = edges[2 * m], o = edges[2 * m + 1];
    int ps = atomicAdd(&cur_s[s], 1);
    slot_s[m] = ps;
    int po = atomicAdd(&cur_o[o], 1);
    slot_o[m] = po;
    srcs[po] = s;
  }
}

// ---------------- pred f32 -> bf16 ----------------
__global__ void cvt_pred(const float* __restrict__ src, bf_t* __restrict__ dst, int n8) {
  int i = blockIdx.x * blockDim.x + threadIdx.x;
  if (i >= n8) return;
  float4 a = ((const float4*)src)[2 * i];
  float4 b = ((const float4*)src)[2 * i + 1];
  bfx8 w;
  w[0] = f2bf(a.x); w[1] = f2bf(a.y); w[2] = f2bf(a.z); w[3] = f2bf(a.w);
  w[4] = f2bf(b.x); w[5] = f2bf(b.y); w[6] = f2bf(b.z); w[7] = f2bf(b.w);
  *(bfx8*)(dst + (size_t)i * 8) = w;
}

// ---------------- weight transpose + cvt: W[K][N] f32 -> Wt[N][K] bf16 ----------------
__global__ void transpose_cvt(const float* __restrict__ W, bf_t* __restrict__ Wt, int K, int N) {
  __shared__ float t[32][33];
  int kb = blockIdx.y << 5, nb = blockIdx.x << 5;
  int tx = threadIdx.x, ty = threadIdx.y;  // 32 x 8
#pragma unroll
  for (int r = 0; r < 32; r += 8) t[ty + r][tx] = W[(size_t)(kb + ty + r) * N + nb + tx];
  __syncthreads();
#pragma unroll
  for (int r = 0; r < 32; r += 8) Wt[(size_t)(nb + ty + r) * K + kb + tx] = f2bf(t[tx][ty + r]);
}

// stage 16 f32 -> 2 swizzled bfx8 LDS chunks
__device__ __forceinline__ void stage16(const float* base, bf_t* stA, int slot0) {
  float4 q0 = ((const float4*)base)[0];
  float4 q1 = ((const float4*)base)[1];
  float4 q2 = ((const float4*)base)[2];
  float4 q3 = ((const float4*)base)[3];
  bfx8 w0, w1;
  w0[0] = f2bf(q0.x); w0[1] = f2bf(q0.y); w0[2] = f2bf(q0.z); w0[3] = f2bf(q0.w);
  w0[4] = f2bf(q1.x); w0[5] = f2bf(q1.y); w0[6] = f2bf(q1.z); w0[7] = f2bf(q1.w);
  w1[0] = f2bf(q2.x); w1[1] = f2bf(q2.y); w1[2] = f2bf(q2.z); w1[3] = f2bf(q2.w);
  w1[4] = f2bf(q3.x); w1[5] = f2bf(q3.y); w1[6] = f2bf(q3.z); w1[7] = f2bf(q3.w);
  *(bfx8*)(stA + slot0 * 8) = w0;
  *(bfx8*)(stA + (slot0 ^ 1) * 8) = w1;
}

// ---------------- MFMA GEMM: C[M,N] = A[M,K](bf16) x Wt[N,K](bf16), 128x128 tile ----------------
// 1D grid, XCD-grouped swizzle: id = (y%8) + 8*((y/8)*CB + c)  ->  all CB col-blocks of
// row-panel y are ≡ y (mod 8) => same XCD, consecutive dispatch => A panel L2-resident.
// MODE 0 (pca1): A = [obj[s] f32 | predh bf16 DMA | obj[o] f32], K=384; epi: +b, leaky, capsule-l2norm -> Xh
// MODE 1 (clf1, atomic pooling): A = m<O_N?Uh2:Xh DMA; epi: bn+leaky; atomicAdd PL / pred_out
// MODE 2 (pca2): A = PL f32 reg-staged; epi like MODE 0 -> Xh
// MODE 3 (clf2): A = Uh2 DMA; epi: bn+leaky -> obj_out f32
// MODE 4 (clf1, slot pooling):  A like MODE 1; epi: val_s[slot_s[m]] / pred_out / val_o[slot_o[m]]
template <int MODE, int CB>
__global__ __launch_bounds__(256) void gemm_mfma(
    const bf_t* __restrict__ Ah, const bf_t* __restrict__ Axh,
    const float* __restrict__ Af, const float* __restrict__ obj,
    const int* __restrict__ edges,
    const bf_t* __restrict__ Wt, const float* __restrict__ bias,
    const float* __restrict__ bng, const float* __restrict__ bnb,
    bf_t* __restrict__ outh, float* __restrict__ outf, float* __restrict__ pool,
    bf_t* __restrict__ vs, bf_t* __restrict__ vo,
    const int* __restrict__ slot_s, const int* __restrict__ slot_o,
    int NRB, int M, int N, int K) {
  // --- XCD-grouped decode ---
  const int id = blockIdx.x;
  const int lane8 = id & 7, tt = id >> 3;
  const int cb = tt % CB, qq = tt / CB;
  const int yb = (qq << 3) + lane8;
  if (yb >= NRB) return;
  const int row0 = yb * 128, col0 = cb * 128;

  __shared__ __align__(16) bf_t As[128 * 32];
  __shared__ __align__(16) bf_t Bs[128 * 32];

  const int tid = threadIdx.x;
  const int w = tid >> 6, l = tid & 63;
  const int wr = w >> 1, wc = w & 1;

  // --- staging pointers (DMA: wave-uniform LDS dest + per-lane global src) ---
  const int srow = l >> 2;
  const int skb = ((l & 3) ^ (srow & 3) ^ ((srow >> 2) & 3)) * 8;  // swizzled src k-chunk
  const bf_t* pB[2];
  bf_t* ldsB[2];
  bf_t* ldsA[2];
  const bf_t* pA[2];
#pragma unroll
  for (int j = 0; j < 2; ++j) {
    int n = col0 + j * 64 + w * 16 + srow;
    pB[j] = Wt + (size_t)n * K + skb;
    ldsB[j] = Bs + (j * 64 + w * 16) * 32;
    ldsA[j] = As + (j * 64 + w * 16) * 32;
  }
  if constexpr (MODE == 1 || MODE == 3 || MODE == 4) {
#pragma unroll
    for (int j = 0; j < 2; ++j) {
      int m = row0 + j * 64 + w * 16 + srow;
      if (MODE == 3) m = min(m, M - 1);
      const bf_t* base = (MODE == 3) ? Ah : ((m < O_N) ? Ah : Axh);
      pA[j] = base + (size_t)m * 512 + skb;
    }
  }
  // reg-staging thread constants
  const int r_ = tid >> 1, h_ = tid & 1;
  const int slot0_ = (2 * h_) ^ (r_ & 3) ^ ((r_ >> 2) & 3);
  bf_t* stA = As + r_ * 32;
  int sIdx = 0, oIdx = 0, mrow = 0;
  if constexpr (MODE == 0) {
    mrow = row0 + r_;
    sIdx = edges[2 * mrow];
    oIdx = edges[2 * mrow + 1];
#pragma unroll
    for (int j = 0; j < 2; ++j)
      pA[j] = Ah + (size_t)(row0 + j * 64 + w * 16 + srow) * 128 + skb;  // predh
  }
  if constexpr (MODE == 2) mrow = min(row0 + r_, M - 1);

  // --- fragment read offsets ---
  const int pkb = ((l >> 4) ^ (l & 3) ^ ((l >> 2) & 3)) * 8;
  int aoff[4], boff[4];
#pragma unroll
  for (int i = 0; i < 4; ++i) {
    aoff[i] = (wr * 64 + i * 16 + (l & 15)) * 32 + pkb;
    boff[i] = (wc * 64 + i * 16 + (l & 15)) * 32 + pkb;
  }

  f32x4 acc[4][4];
  const f32x4 z4 = {0.f, 0.f, 0.f, 0.f};
#pragma unroll
  for (int i = 0; i < 4; ++i)
#pragma unroll
    for (int j = 0; j < 4; ++j) acc[i][j] = z4;

  // --- K loop ---
  for (int k0 = 0; k0 < K; k0 += 32) {
    if (k0) __syncthreads();
#pragma unroll
    for (int j = 0; j < 2; ++j) { gload16(pB[j], ldsB[j]); pB[j] += 32; }
    if constexpr (MODE == 1 || MODE == 3 || MODE == 4) {
#pragma unroll
      for (int j = 0; j < 2; ++j) { gload16(pA[j], ldsA[j]); pA[j] += 32; }
    } else if constexpr (MODE == 0) {
      if (k0 >= 128 && k0 < 256) {
        gload16(pA[0] + (k0 - 128), ldsA[0]);
        gload16(pA[1] + (k0 - 128), ldsA[1]);
      } else {
        const float* base = (k0 < 128)
            ? obj + (size_t)sIdx * 128 + k0 + h_ * 16
            : obj + (size_t)oIdx * 128 + (k0 - 256) + h_ * 16;
        stage16(base, stA, slot0_);
      }
    } else {  // MODE 2
      stage16(Af + (size_t)mrow * K + k0 + h_ * 16, stA, slot0_);
    }
    __syncthreads();
    s16x8 a[4], b[4];
#pragma unroll
    for (int i = 0; i < 4; ++i) a[i] = *(const s16x8*)(As + aoff[i]);
#pragma unroll
    for (int i = 0; i < 4; ++i) b[i] = *(const s16x8*)(Bs + boff[i]);
#pragma unroll
    for (int mi = 0; mi < 4; ++mi)
#pragma unroll
      for (int ni = 0; ni < 4; ++ni)
        acc[mi][ni] = __builtin_amdgcn_mfma_f32_16x16x32_bf16(a[mi], b[ni], acc[mi][ni], 0, 0, 0);
  }

  // --- epilogue ---
  const int lg = l >> 4, li = l & 15;
  const float invs = 1.0f / sqrtf(1.0f + 1e-5f);
  int ncol[4];
  float bsv[4], bgv[4], bbv[4];
#pragma unroll
  for (int ni = 0; ni < 4; ++ni) {
    int n = col0 + wc * 64 + ni * 16 + li;
    ncol[ni] = n;
    bsv[ni] = bias[n];
    if constexpr (MODE == 1 || MODE == 3 || MODE == 4) { bgv[ni] = bng[n] * invs; bbv[ni] = bnb[n]; }
  }
  if constexpr (MODE == 0 || MODE == 2) {
#pragma unroll
    for (int mi = 0; mi < 4; ++mi) {
#pragma unroll
      for (int rg = 0; rg < 4; ++rg) {
        int m = row0 + wr * 64 + mi * 16 + lg * 4 + rg;
        float y[4], ssq = 0.f;
#pragma unroll
        for (int ni = 0; ni < 4; ++ni) {
          float v = leaky(acc[mi][ni][rg] + bsv[ni]);
          y[ni] = v; ssq += v * v;
        }
        ssq += __shfl_xor(ssq, 1); ssq += __shfl_xor(ssq, 2);
        ssq += __shfl_xor(ssq, 4); ssq += __shfl_xor(ssq, 8);
        if (MODE == 2 && m >= M) continue;
        float inv = 1.0f / fmaxf(sqrtf(ssq), 1e-12f);
#pragma unroll
        for (int ni = 0; ni < 4; ++ni)
          outh[(size_t)m * 512 + ncol[ni]] = f2bf(y[ni] * inv);
      }
    }
  } else if constexpr (MODE == 1) {
#pragma unroll
    for (int mi = 0; mi < 4; ++mi) {
#pragma unroll
      for (int rg = 0; rg < 4; ++rg) {
        int m = row0 + wr * 64 + mi * 16 + lg * 4 + rg;
        int sI = edges[2 * m], oI = edges[2 * m + 1];
#pragma unroll
        for (int ni = 0; ni < 4; ++ni) {
          int n = ncol[ni];
          float v = leaky((acc[mi][ni][rg] + bsv[ni]) * bgv[ni] + bbv[ni]);
          if (n < 256)      atomicAdd(&pool[(size_t)sI * 256 + n], v);
          else if (n < 512) outf[(size_t)m * 256 + (n - 256)] = v;
          else              atomicAdd(&pool[(size_t)oI * 256 + (n - 512)], v);
        }
      }
    }
  } else if constexpr (MODE == 4) {
#pragma unroll
    for (int mi = 0; mi < 4; ++mi) {
#pragma unroll
      for (int rg = 0; rg < 4; ++rg) {
        int m = row0 + wr * 64 + mi * 16 + lg * 4 + rg;
        int ss = slot_s[m], so = slot_o[m];
#pragma unroll
        for (int ni = 0; ni < 4; ++ni) {
          int n = ncol[ni];
          float v = leaky((acc[mi][ni][rg] + bsv[ni]) * bgv[ni] + bbv[ni]);
          if (n < 256)      vs[(size_t)ss * 256 + n] = f2bf(v);
          else if (n < 512) outf[(size_t)m * 256 + (n - 256)] = v;
          else              vo[(size_t)so * 256 + (n - 512)] = f2bf(v);
        }
      }
    }
  } else {
#pragma unroll
    for (int mi = 0; mi < 4; ++mi) {
#pragma unroll
      for (int rg = 0; rg < 4; ++rg) {
        int m = row0 + wr * 64 + mi * 16 + lg * 4 + rg;
        if (m >= M) continue;
#pragma unroll
        for (int ni = 0; ni < 4; ++ni) {
          float v = leaky((acc[mi][ni][rg] + bsv[ni]) * bgv[ni] + bbv[ni]);
          outf[(size_t)m * 256 + ncol[ni]] = v;
        }
      }
    }
  }
}

// ---------------- CSR-ordered pooling (no atomics) + divide ----------------
__global__ __launch_bounds__(256) void pool_so(
    const bf_t* __restrict__ vs, const bf_t* __restrict__ vo,
    const int* __restrict__ offs_s, const int* __restrict__ offs_o,
    float* __restrict__ PL, int nnodes) {
  int v = blockIdx.x * 4 + ((int)threadIdx.x >> 6);
  int lane = threadIdx.x & 63;
  if (v >= nnodes) return;
  float sx = 0, sy = 0, sz = 0, sw = 0;
  int a0 = offs_s[v], a1 = offs_s[v + 1];
  for (int e = a0; e < a1; ++e) {
    bfx4 t = *(const bfx4*)(vs + (size_t)e * 256 + lane * 4);
    sx += bf2f(t[0]); sy += bf2f(t[1]); sz += bf2f(t[2]); sw += bf2f(t[3]);
  }
  int b0 = offs_o[v], b1 = offs_o[v + 1];
  for (int e = b0; e < b1; ++e) {
    bfx4 t = *(const bfx4*)(vo + (size_t)e * 256 + lane * 4);
    sx += bf2f(t[0]); sy += bf2f(t[1]); sz += bf2f(t[2]); sw += bf2f(t[3]);
  }
  float inv = 1.0f / fmaxf((float)((a1 - a0) + (b1 - b0)), 1.0f);
  float4 r = {sx * inv, sy * inv, sz * inv, sw * inv};
  *(float4*)(PL + (size_t)v * 256 + lane * 4) = r;
}

// ---------------- per-edge softmax step (shared by both rout paths) ----------------
#define EDGE_STEP(ZR)                                                                   \
  {                                                                                     \
    float d = 0.0f;                                                                     \
    _Pragma("unroll") for (int q = 0; q < 8; ++q) d += (ZR)[q] * ur[q];                 \
    d += __shfl_xor(d, 1); d += __shfl_xor(d, 2); d += __shfl_xor(d, 4);                \
    float mx = d;                                                                       \
    mx = fmaxf(mx, __shfl_xor(mx, 8));                                                  \
    mx = fmaxf(mx, __shfl_xor(mx, 16));                                                 \
    mx = fmaxf(mx, __shfl_xor(mx, 32));                                                 \
    float ex = expf(d - mx);                                                            \
    float sm = ex;                                                                      \
    sm += __shfl_xor(sm, 8); sm += __shfl_xor(sm, 16); sm += __shfl_xor(sm, 32);        \
    float pk = ex / sm;                                                                 \
    _Pragma("unroll") for (int q = 0; q < 8; ++q) ag[q] += pk * (ZR)[q];                \
  }

// ---------------- fused routing layer: wave per node, 3 iters in-register ----------------
__global__ __launch_bounds__(256) void rout_layer(
    const bf_t* __restrict__ Z, bf_t* __restrict__ U,
    const int* __restrict__ offs, const int* __restrict__ srcs, int nnodes) {
  int v = blockIdx.x * 4 + ((int)threadIdx.x >> 6);
  int lane = threadIdx.x & 63;
  if (v >= nnodes) return;
  bfx8 xv = *(const bfx8*)(Z + (size_t)v * 512 + lane * 8);
  float xr[8], ur[8];
#pragma unroll
  for (int q = 0; q < 8; ++q) { xr[q] = bf2f(xv[q]); ur[q] = xr[q]; }
  int e0 = offs[v], e1 = offs[v + 1], deg = e1 - e0;
  if (deg <= 8) {
    bfx8 zc[8];
#pragma unroll
    for (int e = 0; e < 8; ++e)
      if (e < deg) zc[e] = *(const bfx8*)(Z + (size_t)srcs[e0 + e] * 512 + lane * 8);
    for (int it = 0; it < 3; ++it) {
      float ag[8] = {0, 0, 0, 0, 0, 0, 0, 0};
#pragma unroll
      for (int e = 0; e < 8; ++e)
        if (e < deg) {
          float zr[8];
#pragma unroll
          for (int q = 0; q < 8; ++q) zr[q] = bf2f(zc[e][q]);
          EDGE_STEP(zr);
        }
      float ss = 0.0f, wv[8];
#pragma unroll
      for (int q = 0; q < 8; ++q) { wv[q] = ag[q] + xr[q]; ss += wv[q] * wv[q]; }
      ss += __shfl_xor(ss, 1); ss += __shfl_xor(ss, 2); ss += __shfl_xor(ss, 4);
      float inv = 1.0f / fmaxf(sqrtf(ss), 1e-12f);
#pragma unroll
      for (int q = 0; q < 8; ++q) ur[q] = wv[q] * inv;
    }
  } else {
    for (int it = 0; it < 3; ++it) {
      float ag[8] = {0, 0, 0, 0, 0, 0, 0, 0};
      for (int e = e0; e < e1; ++e) {
        bfx8 zv = *(const bfx8*)(Z + (size_t)srcs[e] * 512 + lane * 8);
        float zr[8];
#pragma unroll
        for (int q = 0; q < 8; ++q) zr[q] = bf2f(zv[q]);
        EDGE_STEP(zr);
      }
      float ss = 0.0f, wv[8];
#pragma unroll
      for (int q = 0; q < 8; ++q) { wv[q] = ag[q] + xr[q]; ss += wv[q] * wv[q]; }
      ss += __shfl_xor(ss, 1); ss += __shfl_xor(ss, 2); ss += __shfl_xor(ss, 4);
      float inv = 1.0f / fmaxf(sqrtf(ss), 1e-12f);
#pragma unroll
      for (int q = 0; q < 8; ++q) ur[q] = wv[q] * inv;
    }
  }
  bfx8 ov;
#pragma unroll
  for (int q = 0; q < 8; ++q) ov[q] = f2bf(ur[q]);
  *(bfx8*)(U + (size_t)v * 512 + lane * 8) = ov;
}

// ---------------- pooled /= max(degree,1) (atomic fallback path) ----------------
__global__ void divide_kernel(float* __restrict__ PL,
                              const int* __restrict__ offs_s, const int* __restrict__ offs_o) {
  int v = blockIdx.x;
  int c = threadIdx.x;
  float cnt = (float)((offs_s[v + 1] - offs_s[v]) + (offs_o[v + 1] - offs_o[v]));
  PL[(size_t)v * 256 + c] *= 1.0f / fmaxf(cnt, 1.0f);
}

extern "C" void kernel_launch(void* const* d_in, const int* in_sizes, int n_in,
                              void* d_out, int out_size, void* d_ws, size_t ws_size,
                              hipStream_t stream) {
  const float* obj    = (const float*)d_in[0];
  const float* pred   = (const float*)d_in[1];
  const int*   edges  = (const int*)d_in[2];
  const float* pca_w1 = (const float*)d_in[3];
  const float* pca_b1 = (const float*)d_in[4];
  const float* clf_w1 = (const float*)d_in[5];
  const float* clf_b1 = (const float*)d_in[6];
  const float* bn_g1  = (const float*)d_in[7];
  const float* bn_b1  = (const float*)d_in[8];
  const float* pca_w2 = (const float*)d_in[9];
  const float* pca_b2 = (const float*)d_in[10];
  const float* clf_w2 = (const float*)d_in[11];
  const float* clf_b2 = (const float*)d_in[12];
  const float* bn_g2  = (const float*)d_in[13];
  const float* bn_b2  = (const float*)d_in[14];
  float* outp = (float*)d_out;

  char* ws = (char*)d_ws;
  bf_t* Xh    = (bf_t*)ws;
  bf_t* Uh2   = (bf_t*)(ws + 81920000);
  bf_t* predh = (bf_t*)(ws + 102400000);  // overlay: predh | Uh1 | PL
  bf_t* Uh1   = (bf_t*)(ws + 102400000);
  float* PL   = (float*)(ws + 102400000);
  bf_t* Wt1   = (bf_t*)(ws + 122880000);
  bf_t* Wt2   = (bf_t*)(ws + 123273216);
  bf_t* Wt3   = (bf_t*)(ws + 124059648);
  bf_t* Wt4   = (bf_t*)(ws + 124321792);
  int* I      = (int*)(ws + 124583936);
  int* cnt_s  = I;            int* cnt_o  = I + 20000;
  int* offs_s = I + 40000;    int* offs_o = I + 60001;
  int* cur_s  = I + 80002;    int* cur_o  = I + 100002;
  int* srcs   = I + 120002;
  int* slot_s = I + 200002;   int* slot_o = I + 280002;
  bf_t* val_s = (bf_t*)(ws + 126024000);
  bf_t* val_o = (bf_t*)(ws + 166984000);
  const bool big = (ws_size >= BIG_REQ);

  hipMemsetAsync(cnt_s, 0, 160000, stream);
  count_kernel<<<313, 256, 0, stream>>>(edges, cnt_s, cnt_o);
  scan_kernel<<<2, 1024, 0, stream>>>(cnt_s, cnt_o, offs_s, cur_s, offs_o, cur_o);
  fill_kernel<<<313, 256, 0, stream>>>(edges, cur_s, cur_o, srcs, slot_s, slot_o);

  cvt_pred<<<5000, 256, 0, stream>>>(pred, predh, 1280000);
  transpose_cvt<<<dim3(16, 12), dim3(32, 8), 0, stream>>>(pca_w1, Wt1, 384, 512);
  transpose_cvt<<<dim3(24, 16), dim3(32, 8), 0, stream>>>(clf_w1, Wt2, 512, 768);
  transpose_cvt<<<dim3(16, 8),  dim3(32, 8), 0, stream>>>(pca_w2, Wt3, 256, 512);
  transpose_cvt<<<dim3(8, 16),  dim3(32, 8), 0, stream>>>(clf_w2, Wt4, 512, 256);

  // swizzled 1D grids: 8 * ceil(NRB/8) * CB
  const int g1 = 8 * 79 * 4;   // pca1: NRB=625, CB=4
  const int g2 = 8 * 79 * 6;   // clf1: NRB=625, CB=6
  const int g3 = 8 * 20 * 4;   // pca2: NRB=157, CB=4
  const int g4 = 8 * 20 * 2;   // clf2: NRB=157, CB=2

  // ---- phase 1 ----
  gemm_mfma<0, 4><<<g1, 256, 0, stream>>>(predh, nullptr, nullptr, obj, edges,
                                          Wt1, pca_b1, nullptr, nullptr,
                                          Xh, nullptr, nullptr, nullptr, nullptr,
                                          nullptr, nullptr, 625, T_N, 512, 384);
  rout_layer<<<5000, 256, 0, stream>>>(Xh, Uh1, offs_o, srcs, O_N);
  rout_layer<<<5000, 256, 0, stream>>>(Uh1, Uh2, offs_o, srcs, O_N);
  if (big) {
    gemm_mfma<4, 6><<<g2, 256, 0, stream>>>(Uh2, Xh, nullptr, nullptr, edges,
                                            Wt2, clf_b1, bn_g1, bn_b1,
                                            nullptr, outp + 5120000, nullptr, val_s, val_o,
                                            slot_s, slot_o, 625, T_N, 768, 512);
    pool_so<<<5000, 256, 0, stream>>>(val_s, val_o, offs_s, offs_o, PL, O_N);
  } else {
    hipMemsetAsync(PL, 0, 20480000, stream);
    gemm_mfma<1, 6><<<g2, 256, 0, stream>>>(Uh2, Xh, nullptr, nullptr, edges,
                                            Wt2, clf_b1, bn_g1, bn_b1,
                                            nullptr, outp + 5120000, PL, nullptr, nullptr,
                                            nullptr, nullptr, 625, T_N, 768, 512);
    divide_kernel<<<O_N, 256, 0, stream>>>(PL, offs_s, offs_o);
  }

  // ---- phase 2 (Xh reused as X2) ----
  gemm_mfma<2, 4><<<g3, 256, 0, stream>>>(nullptr, nullptr, PL, nullptr, nullptr,
                                          Wt3, pca_b2, nullptr, nullptr,
                                          Xh, nullptr, nullptr, nullptr, nullptr,
                                          nullptr, nullptr, 157, O_N, 512, 256);
  rout_layer<<<5000, 256, 0, stream>>>(Xh, Uh1, offs_o, srcs, O_N);
  rout_layer<<<5000, 256, 0, stream>>>(Uh1, Uh2, offs_o, srcs, O_N);
  gemm_mfma<3, 2><<<g4, 256, 0, stream>>>(Uh2, nullptr, nullptr, nullptr, nullptr,
                                          Wt4, clf_b2, bn_g2, bn_b2,
                                          nullptr, outp, nullptr, nullptr, nullptr,
                                          nullptr, nullptr, 157, O_N, 256, 512);
}

// Round 7
// 765.147 us; speedup vs baseline: 1.0374x; 1.0026x over previous
//
#include <hip/hip_runtime.h>
#include <math.h>

// DisenTripletGCN — MFMA bf16 GEMMs, double-buffered LDS + counted vmcnt(4)
// (T3/T4 "minimum 2-phase"), all-DMA A staging (gather-DMA for pca1),
// XCD-grouped swizzle, CSR-slot pooling.
// ws layout (bytes):
//   Xh    @ 0           : 80000*512 bf16 = 81,920,000
//   Uh2   @ 81,920,000  : 20000*512 bf16 = 20,480,000
//   OVL   @ 102,400,000 : 20,480,000  (predh | Uh1 | PL-f32(fallback))
//   objh  @ 122,880,000 :  5,120,000
//   PLh   @ 128,000,000 : 10,240,000  (pooled, bf16)
//   Wt1   @ 138,240,000 : 393,216   Wt2 @138,633,216 : 786,432
//   Wt3   @ 139,419,648 : 262,144   Wt4 @139,681,792 : 262,144
//   I     @ 139,944,000 : 360,002 ints -> end 141,384,008
//   val_s @ 141,384,016 : 40,960,000
//   val_o @ 182,344,016 : 40,960,000 -> end 223,304,016
// fallback (atomic pooling) needs only 141.4 MB (< proven 144.5); big path
// needs 223.3 MB (round-5/6 confirmed >= 207.9; heuristically ws ~= 4x out = 409 MB).

#define O_N 20000
#define T_N 80000
#define BIG_REQ 223304016ull

typedef unsigned short bf_t;
typedef bf_t bfx4 __attribute__((ext_vector_type(4)));
typedef bf_t bfx8 __attribute__((ext_vector_type(8)));
typedef __attribute__((ext_vector_type(4))) float f32x4;
typedef __attribute__((ext_vector_type(8))) short s16x8;

#define AS1 __attribute__((address_space(1)))
#define AS3 __attribute__((address_space(3)))

__device__ __forceinline__ float leaky(float y) { return y > 0.0f ? y : 0.01f * y; }
__device__ __forceinline__ float bf2f(bf_t u) {
  union { unsigned int i; float f; } v; v.i = ((unsigned int)u) << 16; return v.f;
}
__device__ __forceinline__ bf_t f2bf(float f) {
  union { float f; unsigned int i; } v; v.f = f;
  unsigned int b = v.i;
  return (bf_t)((b + 0x7FFFu + ((b >> 16) & 1u)) >> 16);  // RNE
}
__device__ __forceinline__ void gload16(const bf_t* g, bf_t* l) {
  __builtin_amdgcn_global_load_lds((const AS1 void*)g, (AS3 void*)l, 16, 0, 0);
}

// ---------------- CSR build ----------------
__global__ void count_kernel(const int* __restrict__ edges, int* cnt_s, int* cnt_o) {
  int m = blockIdx.x * blockDim.x + threadIdx.x;
  if (m < T_N) {
    atomicAdd(&cnt_s[edges[2 * m]], 1);
    atomicAdd(&cnt_o[edges[2 * m + 1]], 1);
  }
}

__global__ void scan_kernel(const int* __restrict__ cnt_s, const int* __restrict__ cnt_o,
                            int* offs_s, int* cur_s, int* offs_o, int* cur_o) {
  const int n = O_N;
  const int* cnt = (blockIdx.x == 0) ? cnt_s : cnt_o;
  int* offs = (blockIdx.x == 0) ? offs_s : offs_o;
  int* cur  = (blockIdx.x == 0) ? cur_s  : cur_o;
  __shared__ int lds[1024];
  __shared__ int sbase;
  if (threadIdx.x == 0) sbase = 0;
  __syncthreads();
  for (int start = 0; start < n; start += 1024) {
    int i = start + (int)threadIdx.x;
    int v = (i < n) ? cnt[i] : 0;
    lds[threadIdx.x] = v;
    __syncthreads();
    for (int off = 1; off < 1024; off <<= 1) {
      int t = (threadIdx.x >= (unsigned)off) ? lds[threadIdx.x - off] : 0;
      __syncthreads();
      lds[threadIdx.x] += t;
      __syncthreads();
    }
    int base = sbase;
    int excl = base + lds[threadIdx.x] - v;
    if (i < n) { offs[i] = excl; cur[i] = excl; }
    __syncthreads();
    if (threadIdx.x == 1023) sbase = base + lds[1023];
    __syncthreads();
  }
  if (threadIdx.x == 0) offs[n] = sbase;
}

__global__ void fill_kernel(const int* __restrict__ edges, int* cur_s, int* cur_o,
                            int* srcs, int* slot_s, int* slot_o) {
  int m = blockIdx.x * blockDim.x + threadIdx.x;
  if (m < T_N) {
    int s = edges[2 * m], o = edges[2 * m + 1];
    int ps = atomicAdd(&cur_s[s], 1);
    slot_s[m] = ps;
    int po = atomicAdd(&cur_o[o], 1);
    slot_o[m] = po;
    srcs[po] = s;
  }
}

// ---------------- f32 -> bf16 bulk convert ----------------
__global__ void cvt_bf16(const float* __restrict__ src, bf_t* __restrict__ dst, int n8) {
  int i = blockIdx.x * blockDim.x + threadIdx.x;
  if (i >= n8) return;
  float4 a = ((const float4*)src)[2 * i];
  float4 b = ((const float4*)src)[2 * i + 1];
  bfx8 w;
  w[0] = f2bf(a.x); w[1] = f2bf(a.y); w[2] = f2bf(a.z); w[3] = f2bf(a.w);
  w[4] = f2bf(b.x); w[5] = f2bf(b.y); w[6] = f2bf(b.z); w[7] = f2bf(b.w);
  *(bfx8*)(dst + (size_t)i * 8) = w;
}

// ---------------- weight transpose + cvt: W[K][N] f32 -> Wt[N][K] bf16 ----------------
__global__ void transpose_cvt(const float* __restrict__ W, bf_t* __restrict__ Wt, int K, int N) {
  __shared__ float t[32][33];
  int kb = blockIdx.y << 5, nb = blockIdx.x << 5;
  int tx = threadIdx.x, ty = threadIdx.y;  // 32 x 8
#pragma unroll
  for (int r = 0; r < 32; r += 8) t[ty + r][tx] = W[(size_t)(kb + ty + r) * N + nb + tx];
  __syncthreads();
#pragma unroll
  for (int r = 0; r < 32; r += 8) Wt[(size_t)(nb + ty + r) * K + kb + tx] = f2bf(t[tx][ty + r]);
}

// ---------------- MFMA GEMM: C[M,N] = A[M,K](bf16) x Wt[N,K](bf16), 128x128 tile ----
// Double-buffered LDS, counted vmcnt(4), raw s_barrier. 1D grid, XCD-grouped:
// id = (y%8) + 8*((y/8)*CB + c) -> col-blocks of one row-panel land on one XCD.
// MODE 0 (pca1): A = gather-DMA [objh[s] | predh | objh[o]] (Ah=predh, Axh=objh);
//                epi: +b, leaky, capsule-l2norm -> Xh
// MODE 1 (clf1 fallback): A = m<O_N?Uh2:Xh DMA; epi: bn+leaky; atomicAdd PL / pred_out
// MODE 2 (pca2): A = PLh DMA (Ah, stride 256, M-guard); epi like MODE 0 -> Xh
// MODE 3 (clf2): A = Uh2 DMA (M-guard); epi: bn+leaky -> obj_out f32
// MODE 4 (clf1): A like MODE 1; epi: val_s[slot_s[m]] / pred_out / val_o[slot_o[m]]
template <int MODE, int CB>
__global__ __launch_bounds__(256) void gemm_mfma(
    const bf_t* __restrict__ Ah, const bf_t* __restrict__ Axh,
    const int* __restrict__ edges,
    const bf_t* __restrict__ Wt, const float* __restrict__ bias,
    const float* __restrict__ bng, const float* __restrict__ bnb,
    bf_t* __restrict__ outh, float* __restrict__ outf, float* __restrict__ pool,
    bf_t* __restrict__ vs, bf_t* __restrict__ vo,
    const int* __restrict__ slot_s, const int* __restrict__ slot_o,
    int NRB, int M, int N, int K) {
  // --- XCD-grouped decode ---
  const int id = blockIdx.x;
  const int lane8 = id & 7, tt = id >> 3;
  const int cb = tt % CB, qq = tt / CB;
  const int yb = (qq << 3) + lane8;
  if (yb >= NRB) return;
  const int row0 = yb * 128, col0 = cb * 128;

  __shared__ __align__(16) bf_t As[2][128 * 32];
  __shared__ __align__(16) bf_t Bs[2][128 * 32];

  const int tid = threadIdx.x;
  const int w = tid >> 6, l = tid & 63;
  const int wr = w >> 1, wc = w & 1;

  // --- staging addresses: wave-uniform LDS dest chunk, per-lane global src ---
  const int srow = l >> 2;
  const int skb = ((l & 3) ^ (srow & 3) ^ ((srow >> 2) & 3)) * 8;  // swizzled src k-chunk
  const bf_t* srcB[2];
  const bf_t* srcA[2];
  const bf_t* srcS[2];
  const bf_t* srcP[2];
  const bf_t* srcO[2];
  int ldsOff[2];
#pragma unroll
  for (int j = 0; j < 2; ++j) {
    int n = col0 + j * 64 + w * 16 + srow;
    srcB[j] = Wt + (size_t)n * K + skb;
    ldsOff[j] = (j * 64 + w * 16) * 32;
    int rowA = row0 + j * 64 + w * 16 + srow;
    if constexpr (MODE == 1 || MODE == 4) {
      srcA[j] = ((rowA < O_N) ? Ah : Axh) + (size_t)rowA * 512 + skb;
    } else if constexpr (MODE == 3) {
      srcA[j] = Ah + (size_t)min(rowA, M - 1) * 512 + skb;
    } else if constexpr (MODE == 2) {
      srcA[j] = Ah + (size_t)min(rowA, M - 1) * 256 + skb;
    } else {  // MODE 0: gather bases
      int s = edges[2 * rowA], o = edges[2 * rowA + 1];
      srcS[j] = Axh + (size_t)s * 128 + skb;
      srcP[j] = Ah + (size_t)rowA * 128 + skb;
      srcO[j] = Axh + (size_t)o * 128 + skb;
    }
  }

  // --- fragment read offsets (swizzle-matched) ---
  const int pkb = ((l >> 4) ^ (l & 3) ^ ((l >> 2) & 3)) * 8;
  int aoff[4], boff[4];
#pragma unroll
  for (int i = 0; i < 4; ++i) {
    aoff[i] = (wr * 64 + i * 16 + (l & 15)) * 32 + pkb;
    boff[i] = (wc * 64 + i * 16 + (l & 15)) * 32 + pkb;
  }

  f32x4 acc[4][4];
  const f32x4 z4 = {0.f, 0.f, 0.f, 0.f};
#pragma unroll
  for (int i = 0; i < 4; ++i)
#pragma unroll
    for (int j = 0; j < 4; ++j) acc[i][j] = z4;

  auto STAGE = [&](int t, int buf) {
    const int k0 = t << 5;
#pragma unroll
    for (int j = 0; j < 2; ++j) {
      if constexpr (MODE == 0) {
        const bf_t* s;
        if (k0 < 128)      s = srcS[j] + k0;
        else if (k0 < 256) s = srcP[j] + (k0 - 128);
        else               s = srcO[j] + (k0 - 256);
        gload16(s, &As[buf][ldsOff[j]]);
      } else {
        gload16(srcA[j] + k0, &As[buf][ldsOff[j]]);
      }
      gload16(srcB[j] + k0, &Bs[buf][ldsOff[j]]);
    }
  };
  auto COMPUTE = [&](int buf) {
    s16x8 a[4], b[4];
#pragma unroll
    for (int i = 0; i < 4; ++i) a[i] = *(const s16x8*)(&As[buf][aoff[i]]);
#pragma unroll
    for (int i = 0; i < 4; ++i) b[i] = *(const s16x8*)(&Bs[buf][boff[i]]);
#pragma unroll
    for (int mi = 0; mi < 4; ++mi)
#pragma unroll
      for (int ni = 0; ni < 4; ++ni)
        acc[mi][ni] = __builtin_amdgcn_mfma_f32_16x16x32_bf16(a[mi], b[ni], acc[mi][ni], 0, 0, 0);
  };

  // --- K loop: 2-phase double buffer, counted vmcnt (nt is even for all modes) ---
  const int nt = K >> 5;
  STAGE(0, 0);
  for (int t = 0; t < nt; t += 2) {
    STAGE(t + 1, 1);
    asm volatile("s_waitcnt vmcnt(4)" ::: "memory");
    __builtin_amdgcn_s_barrier();
    __builtin_amdgcn_sched_barrier(0);
    COMPUTE(0);
    __builtin_amdgcn_sched_barrier(0);
    __builtin_amdgcn_s_barrier();
    if (t + 2 < nt) {
      STAGE(t + 2, 0);
      asm volatile("s_waitcnt vmcnt(4)" ::: "memory");
    } else {
      asm volatile("s_waitcnt vmcnt(0)" ::: "memory");
    }
    __builtin_amdgcn_s_barrier();
    __builtin_amdgcn_sched_barrier(0);
    COMPUTE(1);
    __builtin_amdgcn_sched_barrier(0);
    __builtin_amdgcn_s_barrier();
  }

  // --- epilogue ---
  const int lg = l >> 4, li = l & 15;
  const float invs = 1.0f / sqrtf(1.0f + 1e-5f);
  int ncol[4];
  float bsv[4], bgv[4], bbv[4];
#pragma unroll
  for (int ni = 0; ni < 4; ++ni) {
    int n = col0 + wc * 64 + ni * 16 + li;
    ncol[ni] = n;
    bsv[ni] = bias[n];
    if constexpr (MODE == 1 || MODE == 3 || MODE == 4) { bgv[ni] = bng[n] * invs; bbv[ni] = bnb[n]; }
  }
  if constexpr (MODE == 0 || MODE == 2) {
#pragma unroll
    for (int mi = 0; mi < 4; ++mi) {
#pragma unroll
      for (int rg = 0; rg < 4; ++rg) {
        int m = row0 + wr * 64 + mi * 16 + lg * 4 + rg;
        float y[4], ssq = 0.f;
#pragma unroll
        for (int ni = 0; ni < 4; ++ni) {
          float v = leaky(acc[mi][ni][rg] + bsv[ni]);
          y[ni] = v; ssq += v * v;
        }
        ssq += __shfl_xor(ssq, 1); ssq += __shfl_xor(ssq, 2);
        ssq += __shfl_xor(ssq, 4); ssq += __shfl_xor(ssq, 8);
        if (MODE == 2 && m >= M) continue;
        float inv = 1.0f / fmaxf(sqrtf(ssq), 1e-12f);
#pragma unroll
        for (int ni = 0; ni < 4; ++ni)
          outh[(size_t)m * 512 + ncol[ni]] = f2bf(y[ni] * inv);
      }
    }
  } else if constexpr (MODE == 1) {
#pragma unroll
    for (int mi = 0; mi < 4; ++mi) {
#pragma unroll
      for (int rg = 0; rg < 4; ++rg) {
        int m = row0 + wr * 64 + mi * 16 + lg * 4 + rg;
        int sI = edges[2 * m], oI = edges[2 * m + 1];
#pragma unroll
        for (int ni = 0; ni < 4; ++ni) {
          int n = ncol[ni];
          float v = leaky((acc[mi][ni][rg] + bsv[ni]) * bgv[ni] + bbv[ni]);
          if (n < 256)      atomicAdd(&pool[(size_t)sI * 256 + n], v);
          else if (n < 512) outf[(size_t)m * 256 + (n - 256)] = v;
          else              atomicAdd(&pool[(size_t)oI * 256 + (n - 512)], v);
        }
      }
    }
  } else if constexpr (MODE == 4) {
#pragma unroll
    for (int mi = 0; mi < 4; ++mi) {
#pragma unroll
      for (int rg = 0; rg < 4; ++rg) {
        int m = row0 + wr * 64 + mi * 16 + lg * 4 + rg;
        int ss = slot_s[m], so = slot_o[m];
#pragma unroll
        for (int ni = 0; ni < 4; ++ni) {
          int n = ncol[ni];
          float v = leaky((acc[mi][ni][rg] + bsv[ni]) * bgv[ni] + bbv[ni]);
          if (n < 256)      vs[(size_t)ss * 256 + n] = f2bf(v);
          else if (n < 512) outf[(size_t)m * 256 + (n - 256)] = v;
          else              vo[(size_t)so * 256 + (n - 512)] = f2bf(v);
        }
      }
    }
  } else {
#pragma unroll
    for (int mi = 0; mi < 4; ++mi) {
#pragma unroll
      for (int rg = 0; rg < 4; ++rg) {
        int m = row0 + wr * 64 + mi * 16 + lg * 4 + rg;
        if (m >= M) continue;
#pragma unroll
        for (int ni = 0; ni < 4; ++ni) {
          float v = leaky((acc[mi][ni][rg] + bsv[ni]) * bgv[ni] + bbv[ni]);
          outf[(size_t)m * 256 + ncol[ni]] = v;
        }
      }
    }
  }
}

// ---------------- CSR-ordered pooling (no atomics), divide, bf16 out ----------------
__global__ __launch_bounds__(256) void pool_so(
    const bf_t* __restrict__ vs, const bf_t* __restrict__ vo,
    const int* __restrict__ offs_s, const int* __restrict__ offs_o,
    bf_t* __restrict__ PLh, int nnodes) {
  int v = blockIdx.x * 4 + ((int)threadIdx.x >> 6);
  int lane = threadIdx.x & 63;
  if (v >= nnodes) return;
  float sx = 0, sy = 0, sz = 0, sw = 0;
  int a0 = offs_s[v], a1 = offs_s[v + 1];
  for (int e = a0; e < a1; ++e) {
    bfx4 t = *(const bfx4*)(vs + (size_t)e * 256 + lane * 4);
    sx += bf2f(t[0]); sy += bf2f(t[1]); sz += bf2f(t[2]); sw += bf2f(t[3]);
  }
  int b0 = offs_o[v], b1 = offs_o[v + 1];
  for (int e = b0; e < b1; ++e) {
    bfx4 t = *(const bfx4*)(vo + (size_t)e * 256 + lane * 4);
    sx += bf2f(t[0]); sy += bf2f(t[1]); sz += bf2f(t[2]); sw += bf2f(t[3]);
  }
  float inv = 1.0f / fmaxf((float)((a1 - a0) + (b1 - b0)), 1.0f);
  bfx4 r;
  r[0] = f2bf(sx * inv); r[1] = f2bf(sy * inv);
  r[2] = f2bf(sz * inv); r[3] = f2bf(sw * inv);
  *(bfx4*)(PLh + (size_t)v * 256 + lane * 4) = r;
}

// ---------------- per-edge softmax step ----------------
#define EDGE_STEP(ZR)                                                                   \
  {                                                                                     \
    float d = 0.0f;                                                                     \
    _Pragma("unroll") for (int q = 0; q < 8; ++q) d += (ZR)[q] * ur[q];                 \
    d += __shfl_xor(d, 1); d += __shfl_xor(d, 2); d += __shfl_xor(d, 4);                \
    float mx = d;                                                                       \
    mx = fmaxf(mx, __shfl_xor(mx, 8));                                                  \
    mx = fmaxf(mx, __shfl_xor(mx, 16));                                                 \
    mx = fmaxf(mx, __shfl_xor(mx, 32));                                                 \
    float ex = expf(d - mx);                                                            \
    float sm = ex;                                                                      \
    sm += __shfl_xor(sm, 8); sm += __shfl_xor(sm, 16); sm += __shfl_xor(sm, 32);        \
    float pk = ex / sm;                                                                 \
    _Pragma("unroll") for (int q = 0; q < 8; ++q) ag[q] += pk * (ZR)[q];                \
  }

// ---------------- fused routing layer: wave per node, 3 iters in-register ----------------
__global__ __launch_bounds__(256) void rout_layer(
    const bf_t* __restrict__ Z, bf_t* __restrict__ U,
    const int* __restrict__ offs, const int* __restrict__ srcs, int nnodes) {
  int v = blockIdx.x * 4 + ((int)threadIdx.x >> 6);
  int lane = threadIdx.x & 63;
  if (v >= nnodes) return;
  bfx8 xv = *(const bfx8*)(Z + (size_t)v * 512 + lane * 8);
  float xr[8], ur[8];
#pragma unroll
  for (int q = 0; q < 8; ++q) { xr[q] = bf2f(xv[q]); ur[q] = xr[q]; }
  int e0 = offs[v], e1 = offs[v + 1], deg = e1 - e0;
  if (deg <= 8) {
    bfx8 zc[8];
#pragma unroll
    for (int e = 0; e < 8; ++e)
      if (e < deg) zc[e] = *(const bfx8*)(Z + (size_t)srcs[e0 + e] * 512 + lane * 8);
    for (int it = 0; it < 3; ++it) {
      float ag[8] = {0, 0, 0, 0, 0, 0, 0, 0};
#pragma unroll
      for (int e = 0; e < 8; ++e)
        if (e < deg) {
          float zr[8];
#pragma unroll
          for (int q = 0; q < 8; ++q) zr[q] = bf2f(zc[e][q]);
          EDGE_STEP(zr);
        }
      float ss = 0.0f, wv[8];
#pragma unroll
      for (int q = 0; q < 8; ++q) { wv[q] = ag[q] + xr[q]; ss += wv[q] * wv[q]; }
      ss += __shfl_xor(ss, 1); ss += __shfl_xor(ss, 2); ss += __shfl_xor(ss, 4);
      float inv = 1.0f / fmaxf(sqrtf(ss), 1e-12f);
#pragma unroll
      for (int q = 0; q < 8; ++q) ur[q] = wv[q] * inv;
    }
  } else {
    for (int it = 0; it < 3; ++it) {
      float ag[8] = {0, 0, 0, 0, 0, 0, 0, 0};
      for (int e = e0; e < e1; ++e) {
        bfx8 zv = *(const bfx8*)(Z + (size_t)srcs[e] * 512 + lane * 8);
        float zr[8];
#pragma unroll
        for (int q = 0; q < 8; ++q) zr[q] = bf2f(zv[q]);
        EDGE_STEP(zr);
      }
      float ss = 0.0f, wv[8];
#pragma unroll
      for (int q = 0; q < 8; ++q) { wv[q] = ag[q] + xr[q]; ss += wv[q] * wv[q]; }
      ss += __shfl_xor(ss, 1); ss += __shfl_xor(ss, 2); ss += __shfl_xor(ss, 4);
      float inv = 1.0f / fmaxf(sqrtf(ss), 1e-12f);
#pragma unroll
      for (int q = 0; q < 8; ++q) ur[q] = wv[q] * inv;
    }
  }
  bfx8 ov;
#pragma unroll
  for (int q = 0; q < 8; ++q) ov[q] = f2bf(ur[q]);
  *(bfx8*)(U + (size_t)v * 512 + lane * 8) = ov;
}

// ---------------- fallback: PL f32 /= deg -> PLh bf16 ----------------
__global__ void divide_kernel(const float* __restrict__ PL, bf_t* __restrict__ PLh,
                              const int* __restrict__ offs_s, const int* __restrict__ offs_o) {
  int v = blockIdx.x;
  int c = threadIdx.x;
  float cnt = (float)((offs_s[v + 1] - offs_s[v]) + (offs_o[v + 1] - offs_o[v]));
  PLh[(size_t)v * 256 + c] = f2bf(PL[(size_t)v * 256 + c] / fmaxf(cnt, 1.0f));
}

extern "C" void kernel_launch(void* const* d_in, const int* in_sizes, int n_in,
                              void* d_out, int out_size, void* d_ws, size_t ws_size,
                              hipStream_t stream) {
  const float* obj    = (const float*)d_in[0];
  const float* pred   = (const float*)d_in[1];
  const int*   edges  = (const int*)d_in[2];
  const float* pca_w1 = (const float*)d_in[3];
  const float* pca_b1 = (const float*)d_in[4];
  const float* clf_w1 = (const float*)d_in[5];
  const float* clf_b1 = (const float*)d_in[6];
  const float* bn_g1  = (const float*)d_in[7];
  const float* bn_b1  = (const float*)d_in[8];
  const float* pca_w2 = (const float*)d_in[9];
  const float* pca_b2 = (const float*)d_in[10];
  const float* clf_w2 = (const float*)d_in[11];
  const float* clf_b2 = (const float*)d_in[12];
  const float* bn_g2  = (const float*)d_in[13];
  const float* bn_b2  = (const float*)d_in[14];
  float* outp = (float*)d_out;

  char* ws = (char*)d_ws;
  bf_t* Xh    = (bf_t*)ws;
  bf_t* Uh2   = (bf_t*)(ws + 81920000);
  bf_t* predh = (bf_t*)(ws + 102400000);  // OVL: predh | Uh1 | PL(f32, fallback)
  bf_t* Uh1   = (bf_t*)(ws + 102400000);
  float* PL   = (float*)(ws + 102400000);
  bf_t* objh  = (bf_t*)(ws + 122880000);
  bf_t* PLh   = (bf_t*)(ws + 128000000);
  bf_t* Wt1   = (bf_t*)(ws + 138240000);
  bf_t* Wt2   = (bf_t*)(ws + 138633216);
  bf_t* Wt3   = (bf_t*)(ws + 139419648);
  bf_t* Wt4   = (bf_t*)(ws + 139681792);
  int* I      = (int*)(ws + 139944000);
  int* cnt_s  = I;            int* cnt_o  = I + 20000;
  int* offs_s = I + 40000;    int* offs_o = I + 60001;
  int* cur_s  = I + 80002;    int* cur_o  = I + 100002;
  int* srcs   = I + 120002;
  int* slot_s = I + 200002;   int* slot_o = I + 280002;
  bf_t* val_s = (bf_t*)(ws + 141384016);
  bf_t* val_o = (bf_t*)(ws + 182344016);
  const bool big = (ws_size >= BIG_REQ);

  hipMemsetAsync(cnt_s, 0, 160000, stream);
  count_kernel<<<313, 256, 0, stream>>>(edges, cnt_s, cnt_o);
  scan_kernel<<<2, 1024, 0, stream>>>(cnt_s, cnt_o, offs_s, cur_s, offs_o, cur_o);
  fill_kernel<<<313, 256, 0, stream>>>(edges, cur_s, cur_o, srcs, slot_s, slot_o);

  cvt_bf16<<<5000, 256, 0, stream>>>(pred, predh, 1280000);
  cvt_bf16<<<1250, 256, 0, stream>>>(obj, objh, 320000);
  transpose_cvt<<<dim3(16, 12), dim3(32, 8), 0, stream>>>(pca_w1, Wt1, 384, 512);
  transpose_cvt<<<dim3(24, 16), dim3(32, 8), 0, stream>>>(clf_w1, Wt2, 512, 768);
  transpose_cvt<<<dim3(16, 8),  dim3(32, 8), 0, stream>>>(pca_w2, Wt3, 256, 512);
  transpose_cvt<<<dim3(8, 16),  dim3(32, 8), 0, stream>>>(clf_w2, Wt4, 512, 256);

  // swizzled 1D grids: 8 * ceil(NRB/8) * CB
  const int g1 = 8 * 79 * 4;   // pca1: NRB=625, CB=4
  const int g2 = 8 * 79 * 6;   // clf1: NRB=625, CB=6
  const int g3 = 8 * 20 * 4;   // pca2: NRB=157, CB=4
  const int g4 = 8 * 20 * 2;   // clf2: NRB=157, CB=2

  // ---- phase 1 ----
  gemm_mfma<0, 4><<<g1, 256, 0, stream>>>(predh, objh, edges,
                                          Wt1, pca_b1, nullptr, nullptr,
                                          Xh, nullptr, nullptr, nullptr, nullptr,
                                          nullptr, nullptr, 625, T_N, 512, 384);
  rout_layer<<<5000, 256, 0, stream>>>(Xh, Uh1, offs_o, srcs, O_N);
  rout_layer<<<5000, 256, 0, stream>>>(Uh1, Uh2, offs_o, srcs, O_N);
  if (big) {
    gemm_mfma<4, 6><<<g2, 256, 0, stream>>>(Uh2, Xh, edges,
                                            Wt2, clf_b1, bn_g1, bn_b1,
                                            nullptr, outp + 5120000, nullptr, val_s, val_o,
                                            slot_s, slot_o, 625, T_N, 768, 512);
    pool_so<<<5000, 256, 0, stream>>>(val_s, val_o, offs_s, offs_o, PLh, O_N);
  } else {
    hipMemsetAsync(PL, 0, 20480000, stream);
    gemm_mfma<1, 6><<<g2, 256, 0, stream>>>(Uh2, Xh, edges,
                                            Wt2, clf_b1, bn_g1, bn_b1,
                                            nullptr, outp + 5120000, PL, nullptr, nullptr,
                                            nullptr, nullptr, 625, T_N, 768, 512);
    divide_kernel<<<O_N, 256, 0, stream>>>(PL, PLh, offs_s, offs_o);
  }

  // ---- phase 2 (Xh reused as X2) ----
  gemm_mfma<2, 4><<<g3, 256, 0, stream>>>(PLh, nullptr, nullptr,
                                          Wt3, pca_b2, nullptr, nullptr,
                                          Xh, nullptr, nullptr, nullptr, nullptr,
                                          nullptr, nullptr, 157, O_N, 512, 256);
  rout_layer<<<5000, 256, 0, stream>>>(Xh, Uh1, offs_o, srcs, O_N);
  rout_layer<<<5000, 256, 0, stream>>>(Uh1, Uh2, offs_o, srcs, O_N);
  gemm_mfma<3, 2><<<g4, 256, 0, stream>>>(Uh2, nullptr, nullptr,
                                          Wt4, clf_b2, bn_g2, bn_b2,
                                          nullptr, outp, nullptr, nullptr, nullptr,
                                          nullptr, nullptr, 157, O_N, 256, 512);
}